// Round 1
// baseline (50357.849 us; speedup 1.0000x reference)
//
#include <hip/hip_runtime.h>
#include <hip/hip_bf16.h>

#define V 50257
#define E 256
#define H 512
#define C 16
#define B 256
#define T 128

constexpr float LN_EPS = 1e-5f;

__device__ __forceinline__ float sigm(float x) { return 1.0f / (1.0f + __expf(-x)); }

// ---------------- one-time: xs[t][b][:] = emb[tokens[b][t]] @ Wproj + bproj ----------------
__global__ __launch_bounds__(256) void k_emb(const int* __restrict__ tokens,
                                             const float* __restrict__ emb,
                                             const float* __restrict__ Wproj,
                                             const float* __restrict__ bproj,
                                             float* __restrict__ xs) {
  __shared__ float elds[16][256];
  const int tid = threadIdx.x;
  const int r0 = blockIdx.x * 16;  // row r = t*B + b
#pragma unroll
  for (int i = 0; i < 16; ++i) {
    int r = r0 + i;
    int t = r >> 8, b = r & 255;
    int tok = tokens[b * T + t];
    elds[i][tid] = (tok == 0) ? 0.0f : emb[(size_t)tok * E + tid];  // padding_idx=0
  }
  __syncthreads();
  float acc0[16], acc1[16];
#pragma unroll
  for (int i = 0; i < 16; ++i) { acc0[i] = 0.0f; acc1[i] = 0.0f; }
  for (int k = 0; k < E; k += 4) {
    float w0[4], w1[4];
#pragma unroll
    for (int kk = 0; kk < 4; ++kk) {
      w0[kk] = Wproj[(k + kk) * H + tid];
      w1[kk] = Wproj[(k + kk) * H + tid + 256];
    }
#pragma unroll
    for (int i = 0; i < 16; ++i) {
      float4 e4 = *(const float4*)&elds[i][k];
      acc0[i] = fmaf(e4.x, w0[0], acc0[i]);
      acc0[i] = fmaf(e4.y, w0[1], acc0[i]);
      acc0[i] = fmaf(e4.z, w0[2], acc0[i]);
      acc0[i] = fmaf(e4.w, w0[3], acc0[i]);
      acc1[i] = fmaf(e4.x, w1[0], acc1[i]);
      acc1[i] = fmaf(e4.y, w1[1], acc1[i]);
      acc1[i] = fmaf(e4.z, w1[2], acc1[i]);
      acc1[i] = fmaf(e4.w, w1[3], acc1[i]);
    }
  }
  float bp0 = bproj[tid], bp1 = bproj[tid + 256];
#pragma unroll
  for (int i = 0; i < 16; ++i) {
    size_t r = (size_t)(r0 + i);
    xs[r * H + tid] = acc0[i] + bp0;
    xs[r * H + tid + 256] = acc1[i] + bp1;
  }
}

// ---------------- per step: P = LN(ReLU((xs_t + 0.3*ext) @ Wp[c] + bp)) ----------------
__global__ __launch_bounds__(256) void k_percept(const float* __restrict__ xs_t,
                                                 const float* __restrict__ ext,
                                                 const float* __restrict__ Wp,
                                                 const float* __restrict__ bp,
                                                 const float* __restrict__ ln_g,
                                                 const float* __restrict__ ln_b,
                                                 float* __restrict__ P) {
  __shared__ float xl[16][512];
  __shared__ float mu_s[16], rs_s[16];
  const int tid = threadIdx.x;
  const int c = blockIdx.x >> 4;
  const int b0 = (blockIdx.x & 15) << 4;
  for (int idx = tid; idx < 16 * 512; idx += 256) {
    int r = idx >> 9, col = idx & 511;
    xl[r][col] = xs_t[(b0 + r) * H + col] + 0.3f * ext[(b0 + r) * H + col];
  }
  __syncthreads();
  float acc0[16], acc1[16];
#pragma unroll
  for (int i = 0; i < 16; ++i) { acc0[i] = 0.0f; acc1[i] = 0.0f; }
  const float* Wpc = Wp + (size_t)c * H * H;  // [h_in][h_out]
  for (int k = 0; k < H; k += 4) {
    float w0[4], w1[4];
#pragma unroll
    for (int kk = 0; kk < 4; ++kk) {
      w0[kk] = Wpc[(k + kk) * H + tid];
      w1[kk] = Wpc[(k + kk) * H + tid + 256];
    }
#pragma unroll
    for (int i = 0; i < 16; ++i) {
      float4 x4 = *(const float4*)&xl[i][k];
      acc0[i] = fmaf(x4.x, w0[0], acc0[i]);
      acc0[i] = fmaf(x4.y, w0[1], acc0[i]);
      acc0[i] = fmaf(x4.z, w0[2], acc0[i]);
      acc0[i] = fmaf(x4.w, w0[3], acc0[i]);
      acc1[i] = fmaf(x4.x, w1[0], acc1[i]);
      acc1[i] = fmaf(x4.y, w1[1], acc1[i]);
      acc1[i] = fmaf(x4.z, w1[2], acc1[i]);
      acc1[i] = fmaf(x4.w, w1[3], acc1[i]);
    }
  }
  __syncthreads();  // everyone done reading xl
  float bpv0 = bp[c * H + tid], bpv1 = bp[c * H + tid + 256];
#pragma unroll
  for (int i = 0; i < 16; ++i) {
    xl[i][tid] = fmaxf(acc0[i] + bpv0, 0.0f);
    xl[i][tid + 256] = fmaxf(acc1[i] + bpv1, 0.0f);
  }
  __syncthreads();
  {  // LN stats: 16 threads per row
    int r = tid >> 4, sub = tid & 15;
    float s1 = 0.0f, s2 = 0.0f;
    for (int q = 0; q < 32; ++q) {
      float v = xl[r][sub + (q << 4)];
      s1 += v;
      s2 += v * v;
    }
#pragma unroll
    for (int m = 1; m < 16; m <<= 1) {
      s1 += __shfl_xor(s1, m, 64);
      s2 += __shfl_xor(s2, m, 64);
    }
    if (sub == 0) {
      float mu = s1 * (1.0f / 512.0f);
      float var = s2 * (1.0f / 512.0f) - mu * mu;
      mu_s[r] = mu;
      rs_s[r] = rsqrtf(var + LN_EPS);
    }
  }
  __syncthreads();
  const float* g = ln_g + c * H;
  const float* bb = ln_b + c * H;
  float* Pc = P + ((size_t)c * B + b0) * H;
  for (int idx = tid; idx < 16 * 512; idx += 256) {
    int r = idx >> 9, col = idx & 511;
    float v = (xl[r][col] - mu_s[r]) * rs_s[r];
    Pc[r * H + col] = v * g[col] + bb[col];
  }
}

// ---------------- per step: gates = P@Wih^T + Hst@Whh^T (no bias; bias in k_lstm) ----------------
__global__ __launch_bounds__(256) void k_gates(const float* __restrict__ P,
                                               const float* __restrict__ Hst,
                                               const float* __restrict__ Wih,
                                               const float* __restrict__ Whh,
                                               float* __restrict__ gates) {
  __shared__ float Ap[32][68], Ah[32][68], Bi[32][68], Bh[32][68];
  const int tid = threadIdx.x;
  const int bx = blockIdx.x;
  const int c = bx >> 7;
  const int rem = bx & 127;
  const int b0 = (rem & 3) << 6;
  const int g0 = (rem >> 2) << 6;
  const int tx = tid & 15, ty = tid >> 4;
  const float* Pc = P + (size_t)c * B * H;
  const float* Hc = Hst + (size_t)c * B * H;
  const float* Wi = Wih + (size_t)c * 4 * H * H;  // [g][h]
  const float* Wh = Whh + (size_t)c * 4 * H * H;
  float acc[4][4] = {};
  const int kk = tid & 31, r8 = tid >> 5;
  for (int kb = 0; kb < H; kb += 32) {
#pragma unroll
    for (int q = 0; q < 8; ++q) {
      int row = r8 + (q << 3);
      Ap[kk][row] = Pc[(b0 + row) * H + kb + kk];
      Ah[kk][row] = Hc[(b0 + row) * H + kb + kk];
      Bi[kk][row] = Wi[(size_t)(g0 + row) * H + kb + kk];
      Bh[kk][row] = Wh[(size_t)(g0 + row) * H + kb + kk];
    }
    __syncthreads();
#pragma unroll 4
    for (int k = 0; k < 32; ++k) {
      float a0[4], a1[4], bv0[4], bv1[4];
      *(float4*)a0 = *(const float4*)&Ap[k][ty << 2];
      *(float4*)a1 = *(const float4*)&Ah[k][ty << 2];
      *(float4*)bv0 = *(const float4*)&Bi[k][tx << 2];
      *(float4*)bv1 = *(const float4*)&Bh[k][tx << 2];
#pragma unroll
      for (int i = 0; i < 4; ++i)
#pragma unroll
        for (int j = 0; j < 4; ++j)
          acc[i][j] = fmaf(a0[i], bv0[j], fmaf(a1[i], bv1[j], acc[i][j]));
    }
    __syncthreads();
  }
  float* Gc = gates + (size_t)c * B * 4 * H;
#pragma unroll
  for (int i = 0; i < 4; ++i) {
    float4 st = make_float4(acc[i][0], acc[i][1], acc[i][2], acc[i][3]);
    *(float4*)&Gc[(size_t)(b0 + (ty << 2) + i) * (4 * H) + g0 + (tx << 2)] = st;
  }
}

// ---------------- per step: LSTM elementwise ----------------
__global__ __launch_bounds__(256) void k_lstm(const float* __restrict__ gates,
                                              const float* __restrict__ bih,
                                              const float* __restrict__ bhh,
                                              float* __restrict__ hbuf,
                                              float* __restrict__ cbuf) {
  int idx = blockIdx.x * 256 + threadIdx.x;  // < C*B*H
  int c = idx >> 17;
  int rem = idx & ((1 << 17) - 1);
  int b = rem >> 9;
  int hh = rem & 511;
  const float* Gr = gates + ((size_t)c * B + b) * (4 * H);
  int bo = c * 4 * H + hh;
  float ig = Gr[hh] + bih[bo] + bhh[bo];
  float fg = Gr[H + hh] + bih[bo + H] + bhh[bo + H];
  float gg = Gr[2 * H + hh] + bih[bo + 2 * H] + bhh[bo + 2 * H];
  float og = Gr[3 * H + hh] + bih[bo + 3 * H] + bhh[bo + 3 * H];
  float cn = sigm(fg) * cbuf[idx] + sigm(ig) * tanhf(gg);
  float hn = sigm(og) * tanhf(cn);
  cbuf[idx] = cn;
  hbuf[idx] = hn;
}

// ---------------- per step: abuf = sigmoid(gl)*tanh(h@Wa + ba) ----------------
__global__ __launch_bounds__(256) void k_assoc(const float* __restrict__ Hst,
                                               const float* __restrict__ Wa,
                                               const float* __restrict__ ba,
                                               const float* __restrict__ gl,
                                               float* __restrict__ abuf) {
  __shared__ float Aa[32][68], Bw[32][68];
  const int tid = threadIdx.x;
  const int bx = blockIdx.x;
  const int c = bx >> 5;
  const int rem = bx & 31;
  const int b0 = (rem & 3) << 6;
  const int n0 = (rem >> 2) << 6;
  const int tx = tid & 15, ty = tid >> 4;
  const float* Hc = Hst + (size_t)c * B * H;
  const float* Wc = Wa + (size_t)c * H * H;  // [h_in][h_out]
  float acc[4][4] = {};
  const int kk = tid & 31, r8 = tid >> 5;
  const int n_ = tid & 63, k4 = tid >> 6;
  for (int kb = 0; kb < H; kb += 32) {
#pragma unroll
    for (int q = 0; q < 8; ++q) {
      int row = r8 + (q << 3);
      Aa[kk][row] = Hc[(b0 + row) * H + kb + kk];
      int krow = k4 + (q << 2);
      Bw[krow][n_] = Wc[(size_t)(kb + krow) * H + n0 + n_];
    }
    __syncthreads();
#pragma unroll 4
    for (int k = 0; k < 32; ++k) {
      float a0[4], bv0[4];
      *(float4*)a0 = *(const float4*)&Aa[k][ty << 2];
      *(float4*)bv0 = *(const float4*)&Bw[k][tx << 2];
#pragma unroll
      for (int i = 0; i < 4; ++i)
#pragma unroll
        for (int j = 0; j < 4; ++j) acc[i][j] = fmaf(a0[i], bv0[j], acc[i][j]);
    }
    __syncthreads();
  }
  float gv = sigm(gl[c]);
  float* Ac = abuf + (size_t)c * B * H;
#pragma unroll
  for (int i = 0; i < 4; ++i) {
#pragma unroll
    for (int j = 0; j < 4; ++j)
      acc[i][j] = tanhf(acc[i][j] + ba[c * H + n0 + (tx << 2) + j]) * gv;
    float4 st = make_float4(acc[i][0], acc[i][1], acc[i][2], acc[i][3]);
    *(float4*)&Ac[(size_t)(b0 + (ty << 2) + i) * H + n0 + (tx << 2)] = st;
  }
}

// ---------------- per step: y = mean_c(abuf); write ext and out[:,t,:] ----------------
__global__ __launch_bounds__(256) void k_agg(const float* __restrict__ abuf,
                                             float* __restrict__ ybuf,
                                             float* __restrict__ out, int t) {
  int idx = blockIdx.x * 256 + threadIdx.x;  // < B*H
  float s = 0.0f;
#pragma unroll
  for (int c = 0; c < C; ++c) s += abuf[(size_t)c * (B * H) + idx];
  float y = s * (1.0f / 16.0f);
  ybuf[idx] = y;
  int b = idx >> 9, hh = idx & 511;
  out[((size_t)b * T + t) * H + hh] = y;
}

extern "C" void kernel_launch(void* const* d_in, const int* in_sizes, int n_in,
                              void* d_out, int out_size, void* d_ws, size_t ws_size,
                              hipStream_t stream) {
  const int* tokens = (const int*)d_in[0];
  const float* emb = (const float*)d_in[1];
  const float* Wproj = (const float*)d_in[2];
  const float* bproj = (const float*)d_in[3];
  const float* Wp = (const float*)d_in[4];
  const float* bp = (const float*)d_in[5];
  const float* ln_g = (const float*)d_in[6];
  const float* ln_b = (const float*)d_in[7];
  const float* Wih = (const float*)d_in[8];
  const float* bih = (const float*)d_in[9];
  const float* Whh = (const float*)d_in[10];
  const float* bhh = (const float*)d_in[11];
  const float* Wa = (const float*)d_in[12];
  const float* ba = (const float*)d_in[13];
  const float* gl = (const float*)d_in[14];
  float* out = (float*)d_out;

  float* ws = (float*)d_ws;
  float* xs = ws;                                // T*B*H      = 16,777,216
  float* Pbuf = xs + (size_t)T * B * H;          // C*B*H      =  2,097,152
  float* gates = Pbuf + (size_t)C * B * H;       // C*B*4H     =  8,388,608
  float* abuf = gates + (size_t)C * B * 4 * H;   // C*B*H
  float* hbuf = abuf + (size_t)C * B * H;        // C*B*H
  float* cbuf = hbuf + (size_t)C * B * H;        // C*B*H
  float* ybuf = cbuf + (size_t)C * B * H;        // B*H
  // zero h, c, ext (contiguous region) every call
  hipMemsetAsync(hbuf, 0, (size_t)(2 * C * B * H + B * H) * sizeof(float), stream);

  k_emb<<<T * B / 16, 256, 0, stream>>>(tokens, emb, Wproj, bproj, xs);

  for (int t = 0; t < T; ++t) {
    k_percept<<<C * (B / 16), 256, 0, stream>>>(xs + (size_t)t * B * H, ybuf, Wp, bp,
                                                ln_g, ln_b, Pbuf);
    k_gates<<<C * (B / 64) * (4 * H / 64), 256, 0, stream>>>(Pbuf, hbuf, Wih, Whh, gates);
    k_lstm<<<C * B * H / 256, 256, 0, stream>>>(gates, bih, bhh, hbuf, cbuf);
    k_assoc<<<C * (B / 64) * (H / 64), 256, 0, stream>>>(hbuf, Wa, ba, gl, abuf);
    k_agg<<<B * H / 256, 256, 0, stream>>>(abuf, ybuf, out, t);
  }
}

// Round 2
// 8628.407 us; speedup vs baseline: 5.8363x; 5.8363x over previous
//
#include <hip/hip_runtime.h>
#include <hip/hip_bf16.h>

#define V 50257
#define E 256
#define H 512
#define C 16
#define B 256
#define T 128

typedef _Float16 f16x8 __attribute__((ext_vector_type(8)));
typedef _Float16 f16x4 __attribute__((ext_vector_type(4)));
typedef float f32x4 __attribute__((ext_vector_type(4)));

__device__ __forceinline__ float sigm(float x) { return 1.0f / (1.0f + __expf(-x)); }

__device__ __forceinline__ void gload16(const _Float16* g, _Float16* l) {
  __builtin_amdgcn_global_load_lds((const __attribute__((address_space(1))) unsigned*)g,
                                   (__attribute__((address_space(3))) unsigned*)l, 16, 0, 0);
}

// ---------------- one-time: xs_h[t*B+b][:] = f16(emb[tokens[b][t]] @ Wproj + bproj) ----------------
__global__ __launch_bounds__(256) void k_emb(const int* __restrict__ tokens,
                                             const float* __restrict__ emb,
                                             const float* __restrict__ Wproj,
                                             const float* __restrict__ bproj,
                                             _Float16* __restrict__ xs_h) {
  __shared__ float elds[16][256];
  const int tid = threadIdx.x;
  const int r0 = blockIdx.x * 16;  // row r = t*B + b
#pragma unroll
  for (int i = 0; i < 16; ++i) {
    int r = r0 + i;
    int t = r >> 8, b = r & 255;
    int tok = tokens[b * T + t];
    elds[i][tid] = (tok == 0) ? 0.0f : emb[(size_t)tok * E + tid];  // padding_idx=0
  }
  __syncthreads();
  float acc0[16], acc1[16];
#pragma unroll
  for (int i = 0; i < 16; ++i) { acc0[i] = 0.0f; acc1[i] = 0.0f; }
  for (int k = 0; k < E; k += 4) {
    float w0[4], w1[4];
#pragma unroll
    for (int kk = 0; kk < 4; ++kk) {
      w0[kk] = Wproj[(k + kk) * H + tid];
      w1[kk] = Wproj[(k + kk) * H + tid + 256];
    }
#pragma unroll
    for (int i = 0; i < 16; ++i) {
      float4 e4 = *(const float4*)&elds[i][k];
      acc0[i] = fmaf(e4.x, w0[0], acc0[i]);
      acc0[i] = fmaf(e4.y, w0[1], acc0[i]);
      acc0[i] = fmaf(e4.z, w0[2], acc0[i]);
      acc0[i] = fmaf(e4.w, w0[3], acc0[i]);
      acc1[i] = fmaf(e4.x, w1[0], acc1[i]);
      acc1[i] = fmaf(e4.y, w1[1], acc1[i]);
      acc1[i] = fmaf(e4.z, w1[2], acc1[i]);
      acc1[i] = fmaf(e4.w, w1[3], acc1[i]);
    }
  }
  float bp0 = bproj[tid], bp1 = bproj[tid + 256];
#pragma unroll
  for (int i = 0; i < 16; ++i) {
    size_t r = (size_t)(r0 + i);
    xs_h[r * H + tid] = (_Float16)(acc0[i] + bp0);
    xs_h[r * H + tid + 256] = (_Float16)(acc1[i] + bp1);
  }
}

// ---------------- weight prep (once per call) ----------------
// WgT[c][n][k2] (f16): k2<512 -> Wih[c][n][k2], else Whh[c][n][k2-512]
__global__ __launch_bounds__(256) void k_cvt_wg(const float* __restrict__ Wih,
                                                const float* __restrict__ Whh,
                                                _Float16* __restrict__ WgT) {
  for (size_t i4 = ((size_t)blockIdx.x * 256 + threadIdx.x) * 4; i4 < (size_t)33554432;
       i4 += (size_t)gridDim.x * 1024) {
    size_t c = i4 >> 21;
    size_t rem = i4 & 2097151;
    size_t n = rem >> 10;
    size_t k2 = rem & 1023;
    const float* src = (k2 < 512) ? (Wih + (c * 2048 + n) * 512 + k2)
                                  : (Whh + (c * 2048 + n) * 512 + (k2 - 512));
    float4 v = *(const float4*)src;
    f16x4 o;
    o[0] = (_Float16)v.x; o[1] = (_Float16)v.y; o[2] = (_Float16)v.z; o[3] = (_Float16)v.w;
    *(f16x4*)&WgT[i4] = o;
  }
}

// transpose [c][k][n] f32 -> [c][n][k] f16 (512x512 per c)
__global__ __launch_bounds__(256) void k_cvt_tr(const float* __restrict__ W,
                                                _Float16* __restrict__ WT) {
  __shared__ float tl[64][65];
  const int tid = threadIdx.x;
  const int c = blockIdx.z;
  const int k0 = blockIdx.y * 64, n0 = blockIdx.x * 64;
  const float* Wc = W + (size_t)c * 262144;
#pragma unroll
  for (int q = 0; q < 16; ++q) {
    int idx = q * 256 + tid;
    int r = idx >> 6, cc = idx & 63;
    tl[r][cc] = Wc[(size_t)(k0 + r) * 512 + n0 + cc];
  }
  __syncthreads();
  _Float16* WTc = WT + (size_t)c * 262144;
#pragma unroll
  for (int q = 0; q < 16; ++q) {
    int idx = q * 256 + tid;
    int rr = idx >> 6, cc = idx & 63;
    WTc[(size_t)(n0 + rr) * 512 + k0 + cc] = (_Float16)tl[cc][rr];
  }
}

__global__ __launch_bounds__(256) void k_bias(const float* __restrict__ bih,
                                              const float* __restrict__ bhh,
                                              float* __restrict__ bsum) {
  int i = blockIdx.x * 256 + threadIdx.x;
  if (i < C * 4 * H) bsum[i] = bih[i] + bhh[i];
}

// ---------------- batched f16 MFMA GEMM, 128x128xBK64 tile, 4 waves ----------------
// EPI 0: percept (bias+relu, f16 out)  1: gates (bias, f16 out)  2: assoc (tanh(.+ba)*gate, f16 out)
template <int EPI, int KK, int LDA, int LDB, int ACS, int BCS, int OLD, int BLD>
__global__ __launch_bounds__(256, 2) void k_gemm(const _Float16* __restrict__ A,
                                                 const _Float16* __restrict__ Bm,
                                                 _Float16* __restrict__ hout,
                                                 const float* __restrict__ bias,
                                                 const float* __restrict__ gl) {
  __shared__ _Float16 Asl[128 * 64];
  __shared__ _Float16 Bsl[128 * 64];
  const int tid = threadIdx.x;
  const int w = tid >> 6, l = tid & 63;
  const int c = blockIdx.z;
  const int m0 = blockIdx.y * 128, n0 = blockIdx.x * 128;
  const _Float16* Ab = A + (size_t)c * ACS + (size_t)m0 * LDA;
  const _Float16* Bb = Bm + (size_t)c * BCS + (size_t)n0 * LDB;
  f32x4 acc[4][4];
#pragma unroll
  for (int i = 0; i < 4; ++i)
#pragma unroll
    for (int j = 0; j < 4; ++j) acc[i][j] = (f32x4)0.0f;
  const int wm = (w >> 1) * 64, wn = (w & 1) * 64;
  const int srow = l >> 3, sj = l & 7;
#pragma unroll 1
  for (int kb = 0; kb < KK / 64; ++kb) {
    // stage: LDS linear dest, XOR-swizzled global source (chunk j stored at j^(r&7))
#pragma unroll
    for (int q = 0; q < 4; ++q) {
      int r = w * 32 + q * 8 + srow;
      int gj = sj ^ (r & 7);
      gload16(Ab + (size_t)r * LDA + kb * 64 + gj * 8, &Asl[(w * 32 + q * 8) * 64]);
      gload16(Bb + (size_t)r * LDB + kb * 64 + gj * 8, &Bsl[(w * 32 + q * 8) * 64]);
    }
    __syncthreads();
#pragma unroll
    for (int s2 = 0; s2 < 2; ++s2) {
      f16x8 af[4], bf[4];
#pragma unroll
      for (int i = 0; i < 4; ++i) {
        int R = wm + i * 16 + (l & 15);
        int p = (s2 * 4 + (l >> 4)) ^ (R & 7);
        af[i] = *(const f16x8*)&Asl[R * 64 + p * 8];
        int RN = wn + i * 16 + (l & 15);
        int pn = (s2 * 4 + (l >> 4)) ^ (RN & 7);
        bf[i] = *(const f16x8*)&Bsl[RN * 64 + pn * 8];
      }
#pragma unroll
      for (int i = 0; i < 4; ++i)
#pragma unroll
        for (int j = 0; j < 4; ++j)
          acc[i][j] = __builtin_amdgcn_mfma_f32_16x16x32_f16(af[i], bf[j], acc[i][j], 0, 0, 0);
    }
    __syncthreads();
  }
  float gv = 0.0f;
  if (EPI == 2) gv = sigm(gl[c]);
  const int rl = (l >> 4) * 4, cl = l & 15;
#pragma unroll
  for (int i = 0; i < 4; ++i) {
#pragma unroll
    for (int j = 0; j < 4; ++j) {
      int gc = n0 + wn + j * 16 + cl;
      float bv = bias[(size_t)c * BLD + gc];
#pragma unroll
      for (int rg = 0; rg < 4; ++rg) {
        int gr = m0 + wm + i * 16 + rl + rg;
        float v = acc[i][j][rg] + bv;
        if (EPI == 0) v = fmaxf(v, 0.0f);
        if (EPI == 2) v = tanhf(v) * gv;
        hout[(size_t)c * (256 * (size_t)OLD) + (size_t)gr * OLD + gc] = (_Float16)v;
      }
    }
  }
}

// ---------------- LN in place on Aq P-region (rows C*B, cols 0..511, ld 1024) ----------------
__global__ __launch_bounds__(256) void k_ln(_Float16* __restrict__ Aq,
                                            const float* __restrict__ g,
                                            const float* __restrict__ b) {
  int row = blockIdx.x * 4 + (threadIdx.x >> 6);
  int l = threadIdx.x & 63;
  int c = row >> 8;
  _Float16* p = Aq + (size_t)row * 1024 + l * 8;
  f16x8 v = *(const f16x8*)p;
  float vf[8];
  float s1 = 0.0f, s2 = 0.0f;
#pragma unroll
  for (int j = 0; j < 8; ++j) {
    vf[j] = (float)v[j];
    s1 += vf[j];
    s2 += vf[j] * vf[j];
  }
#pragma unroll
  for (int m = 1; m < 64; m <<= 1) {
    s1 += __shfl_xor(s1, m, 64);
    s2 += __shfl_xor(s2, m, 64);
  }
  float mu = s1 * (1.0f / 512.0f);
  float var = s2 * (1.0f / 512.0f) - mu * mu;
  float rs = rsqrtf(var + 1e-5f);
  int col0 = l * 8;
#pragma unroll
  for (int j = 0; j < 8; ++j) {
    float o = (vf[j] - mu) * rs * g[c * 512 + col0 + j] + b[c * 512 + col0 + j];
    v[j] = (_Float16)o;
  }
  *(f16x8*)p = v;
}

// ---------------- LSTM elementwise: gates(f16,+bias) -> c(f32), h(f16 into Aq cols 512..1023) ----------------
__global__ __launch_bounds__(256) void k_lstm(const _Float16* __restrict__ gq,
                                              float* __restrict__ cbuf,
                                              _Float16* __restrict__ Aq) {
  int idx = blockIdx.x * 256 + threadIdx.x;  // < C*B*H/4 = 524288
  int c = idx >> 15, rem = idx & 32767;
  int b = rem >> 7, h4 = (rem & 127) << 2;
  const _Float16* Gr = gq + ((size_t)c * 256 + b) * 2048;
  f16x4 ig4 = *(const f16x4*)&Gr[h4];
  f16x4 fg4 = *(const f16x4*)&Gr[512 + h4];
  f16x4 gg4 = *(const f16x4*)&Gr[1024 + h4];
  f16x4 og4 = *(const f16x4*)&Gr[1536 + h4];
  float4 cv = *(float4*)&cbuf[(size_t)idx * 4];
  float* cvp = &cv.x;
  f16x4 hh;
#pragma unroll
  for (int j = 0; j < 4; ++j) {
    float cn = sigm((float)fg4[j]) * cvp[j] + sigm((float)ig4[j]) * tanhf((float)gg4[j]);
    cvp[j] = cn;
    hh[j] = (_Float16)(sigm((float)og4[j]) * tanhf(cn));
  }
  *(float4*)&cbuf[(size_t)idx * 4] = cv;
  *(f16x4*)&Aq[((size_t)c * 256 + b) * 1024 + 512 + h4] = hh;
}

// ---------------- agg: y = mean_c(abuf); out[:,t,:]; xq_next = f16(xs[t+1] + 0.3 y) ----------------
__global__ __launch_bounds__(256) void k_agg(const _Float16* __restrict__ abuf,
                                             const _Float16* __restrict__ xs_h,
                                             _Float16* __restrict__ xq,
                                             float* __restrict__ out, int t) {
  int idx = blockIdx.x * 256 + threadIdx.x;  // < B*H/4
  int i4 = idx * 4;
  float s[4] = {0.0f, 0.0f, 0.0f, 0.0f};
#pragma unroll
  for (int c = 0; c < 16; ++c) {
    f16x4 a = *(const f16x4*)&abuf[(size_t)c * 131072 + i4];
#pragma unroll
    for (int j = 0; j < 4; ++j) s[j] += (float)a[j];
  }
  int b = i4 >> 9, h = i4 & 511;
  float4 y4;
  float* yp = &y4.x;
#pragma unroll
  for (int j = 0; j < 4; ++j) yp[j] = s[j] * (1.0f / 16.0f);
  *(float4*)&out[((size_t)b * T + t) * 512 + h] = y4;
  if (t + 1 < T) {
    f16x4 xs4 = *(const f16x4*)&xs_h[(size_t)(t + 1) * 131072 + i4];
    f16x4 xn;
#pragma unroll
    for (int j = 0; j < 4; ++j) xn[j] = (_Float16)((float)xs4[j] + 0.3f * yp[j]);
    *(f16x4*)&xq[i4] = xn;
  }
}

extern "C" void kernel_launch(void* const* d_in, const int* in_sizes, int n_in,
                              void* d_out, int out_size, void* d_ws, size_t ws_size,
                              hipStream_t stream) {
  const int* tokens = (const int*)d_in[0];
  const float* emb = (const float*)d_in[1];
  const float* Wproj = (const float*)d_in[2];
  const float* bproj = (const float*)d_in[3];
  const float* Wp = (const float*)d_in[4];
  const float* bp = (const float*)d_in[5];
  const float* ln_g = (const float*)d_in[6];
  const float* ln_b = (const float*)d_in[7];
  const float* Wih = (const float*)d_in[8];
  const float* bih = (const float*)d_in[9];
  const float* Whh = (const float*)d_in[10];
  const float* bhh = (const float*)d_in[11];
  const float* Wa = (const float*)d_in[12];
  const float* ba = (const float*)d_in[13];
  const float* gl = (const float*)d_in[14];
  float* out = (float*)d_out;

  char* w8 = (char*)d_ws;
  _Float16* xs_h = (_Float16*)w8;                        // 33,554,432 B
  _Float16* Aq = (_Float16*)(w8 + 33554432);             // 16,777,216 B  [c][256][1024] P|h
  _Float16* gatesq = (_Float16*)(w8 + 50331648);         // 16,777,216 B
  float* cbuf = (float*)(w8 + 67108864);                 //  8,388,608 B
  _Float16* abuf = (_Float16*)(w8 + 75497472);           //  4,194,304 B
  _Float16* xq = (_Float16*)(w8 + 79691776);             //    262,144 B
  _Float16* WpT = (_Float16*)(w8 + 79953920);            //  8,388,608 B
  _Float16* WaT = (_Float16*)(w8 + 88342528);            //  8,388,608 B
  _Float16* WgT = (_Float16*)(w8 + 96731136);            // 67,108,864 B
  float* bsum = (float*)(w8 + 163840000);                //    131,072 B (end 163,971,072)

  hipMemsetAsync(Aq, 0, 16777216, stream);   // zeros P and h regions (h0 = 0)
  hipMemsetAsync(cbuf, 0, 8388608, stream);  // c0 = 0

  k_cvt_wg<<<4096, 256, 0, stream>>>(Wih, Whh, WgT);
  k_cvt_tr<<<dim3(8, 8, 16), 256, 0, stream>>>(Wp, WpT);
  k_cvt_tr<<<dim3(8, 8, 16), 256, 0, stream>>>(Wa, WaT);
  k_bias<<<128, 256, 0, stream>>>(bih, bhh, bsum);
  k_emb<<<T * B / 16, 256, 0, stream>>>(tokens, emb, Wproj, bproj, xs_h);
  hipMemcpyAsync(xq, xs_h, 262144, hipMemcpyDeviceToDevice, stream);  // x0 (ext=0)

  for (int t = 0; t < T; ++t) {
    // percept: A=xq[256][512] (shared over c), B=WpT[c][512][512] -> Aq P region (relu)
    k_gemm<0, 512, 512, 512, 0, 262144, 1024, 512>
        <<<dim3(4, 2, 16), 256, 0, stream>>>(xq, WpT, Aq, bp, nullptr);
    k_ln<<<1024, 256, 0, stream>>>(Aq, ln_g, ln_b);
    // gates: A=Aq[c][256][1024] (P|h), B=WgT[c][2048][1024] -> gatesq (+bsum)
    k_gemm<1, 1024, 1024, 1024, 262144, 2097152, 2048, 2048>
        <<<dim3(16, 2, 16), 256, 0, stream>>>(Aq, WgT, gatesq, bsum, nullptr);
    k_lstm<<<2048, 256, 0, stream>>>(gatesq, cbuf, Aq);
    // assoc: A=Aq h region (ld 1024), B=WaT[c][512][512] -> abuf (tanh * gate)
    k_gemm<2, 512, 1024, 512, 262144, 262144, 512, 512>
        <<<dim3(4, 2, 16), 256, 0, stream>>>(Aq + 512, WaT, abuf, ba, gl);
    k_agg<<<128, 256, 0, stream>>>(abuf, xs_h, xq, out, t);
  }
}

// Round 3
// 7975.025 us; speedup vs baseline: 6.3144x; 1.0819x over previous
//
#include <hip/hip_runtime.h>
#include <hip/hip_bf16.h>

#define V 50257
#define E 256
#define H 512
#define C 16
#define B 256
#define T 128

typedef _Float16 f16x8 __attribute__((ext_vector_type(8)));
typedef _Float16 f16x4 __attribute__((ext_vector_type(4)));
typedef float f32x4 __attribute__((ext_vector_type(4)));

__device__ __forceinline__ float sigm(float x) { return 1.0f / (1.0f + __expf(-x)); }

__device__ __forceinline__ void gload16(const _Float16* g, _Float16* l) {
  __builtin_amdgcn_global_load_lds((const __attribute__((address_space(1))) unsigned*)g,
                                   (__attribute__((address_space(3))) unsigned*)l, 16, 0, 0);
}

// ---------------- one-time: xs_h[t*B+b][:] = f16(emb[tokens[b][t]] @ Wproj + bproj) ----------------
__global__ __launch_bounds__(256) void k_emb(const int* __restrict__ tokens,
                                             const float* __restrict__ emb,
                                             const float* __restrict__ Wproj,
                                             const float* __restrict__ bproj,
                                             _Float16* __restrict__ xs_h) {
  __shared__ float elds[16][256];
  const int tid = threadIdx.x;
  const int r0 = blockIdx.x * 16;  // row r = t*B + b
#pragma unroll
  for (int i = 0; i < 16; ++i) {
    int r = r0 + i;
    int t = r >> 8, b = r & 255;
    int tok = tokens[b * T + t];
    elds[i][tid] = (tok == 0) ? 0.0f : emb[(size_t)tok * E + tid];  // padding_idx=0
  }
  __syncthreads();
  float acc0[16], acc1[16];
#pragma unroll
  for (int i = 0; i < 16; ++i) { acc0[i] = 0.0f; acc1[i] = 0.0f; }
  for (int k = 0; k < E; k += 4) {
    float w0[4], w1[4];
#pragma unroll
    for (int kk = 0; kk < 4; ++kk) {
      w0[kk] = Wproj[(k + kk) * H + tid];
      w1[kk] = Wproj[(k + kk) * H + tid + 256];
    }
#pragma unroll
    for (int i = 0; i < 16; ++i) {
      float4 e4 = *(const float4*)&elds[i][k];
      acc0[i] = fmaf(e4.x, w0[0], acc0[i]);
      acc0[i] = fmaf(e4.y, w0[1], acc0[i]);
      acc0[i] = fmaf(e4.z, w0[2], acc0[i]);
      acc0[i] = fmaf(e4.w, w0[3], acc0[i]);
      acc1[i] = fmaf(e4.x, w1[0], acc1[i]);
      acc1[i] = fmaf(e4.y, w1[1], acc1[i]);
      acc1[i] = fmaf(e4.z, w1[2], acc1[i]);
      acc1[i] = fmaf(e4.w, w1[3], acc1[i]);
    }
  }
  float bp0 = bproj[tid], bp1 = bproj[tid + 256];
#pragma unroll
  for (int i = 0; i < 16; ++i) {
    size_t r = (size_t)(r0 + i);
    xs_h[r * H + tid] = (_Float16)(acc0[i] + bp0);
    xs_h[r * H + tid + 256] = (_Float16)(acc1[i] + bp1);
  }
}

// ---------------- weight prep (once per call) ----------------
// Gate-interleaved layout: n' = (hh>>4)*64 + gate*16 + (hh&15); k2<512 -> Wih, else Whh.
__global__ __launch_bounds__(256) void k_cvt_wg(const float* __restrict__ Wih,
                                                const float* __restrict__ Whh,
                                                _Float16* __restrict__ WgT) {
  for (size_t i4 = ((size_t)blockIdx.x * 256 + threadIdx.x) * 4; i4 < (size_t)33554432;
       i4 += (size_t)gridDim.x * 1024) {
    size_t c = i4 >> 21;
    size_t rem = i4 & 2097151;
    size_t np = rem >> 10;  // n' 0..2047
    size_t k2 = rem & 1023;
    int gate = (int)((np >> 4) & 3);
    int hh = (int)(((np >> 6) << 4) | (np & 15));
    size_t n = (size_t)gate * 512 + hh;
    const float* src = (k2 < 512) ? (Wih + (c * 2048 + n) * 512 + k2)
                                  : (Whh + (c * 2048 + n) * 512 + (k2 - 512));
    float4 v = *(const float4*)src;
    f16x4 o;
    o[0] = (_Float16)v.x; o[1] = (_Float16)v.y; o[2] = (_Float16)v.z; o[3] = (_Float16)v.w;
    *(f16x4*)&WgT[i4] = o;
  }
}

// transpose [c][k][n] f32 -> [c][n][k] f16 (512x512 per c)
__global__ __launch_bounds__(256) void k_cvt_tr(const float* __restrict__ W,
                                                _Float16* __restrict__ WT) {
  __shared__ float tl[64][65];
  const int tid = threadIdx.x;
  const int c = blockIdx.z;
  const int k0 = blockIdx.y * 64, n0 = blockIdx.x * 64;
  const float* Wc = W + (size_t)c * 262144;
#pragma unroll
  for (int q = 0; q < 16; ++q) {
    int idx = q * 256 + tid;
    int r = idx >> 6, cc = idx & 63;
    tl[r][cc] = Wc[(size_t)(k0 + r) * 512 + n0 + cc];
  }
  __syncthreads();
  _Float16* WTc = WT + (size_t)c * 262144;
#pragma unroll
  for (int q = 0; q < 16; ++q) {
    int idx = q * 256 + tid;
    int rr = idx >> 6, cc = idx & 63;
    WTc[(size_t)(n0 + rr) * 512 + k0 + cc] = (_Float16)tl[cc][rr];
  }
}

// bsum in interleaved n' layout
__global__ __launch_bounds__(256) void k_bias(const float* __restrict__ bih,
                                              const float* __restrict__ bhh,
                                              float* __restrict__ bsum) {
  int i = blockIdx.x * 256 + threadIdx.x;
  if (i < C * 4 * H) {
    int c = i >> 11, np = i & 2047;
    int gate = (np >> 4) & 3;
    int hh = ((np >> 6) << 4) | (np & 15);
    int n = gate * 512 + hh;
    bsum[i] = bih[c * 2048 + n] + bhh[c * 2048 + n];
  }
}

// ---------------- batched f16 MFMA GEMM, 128x128xBK64 tile, 4 waves ----------------
// EPI 0: percept (bias+relu, f16 out)   2: assoc (tanh(.+ba)*gate, f16 out)
// EPI 3: gates+LSTM fused (interleaved gate cols; updates cstate f32, writes h f16)
template <int EPI, int KK, int LDA, int LDB, int ACS, int BCS, int OLD, int BLD>
__global__ __launch_bounds__(256, 2) void k_gemm(const _Float16* __restrict__ A,
                                                 const _Float16* __restrict__ Bm,
                                                 _Float16* __restrict__ hout,
                                                 const float* __restrict__ bias,
                                                 const float* __restrict__ gl,
                                                 float* __restrict__ cstate,
                                                 _Float16* __restrict__ hdst) {
  __shared__ _Float16 Asl[128 * 64];
  __shared__ _Float16 Bsl[128 * 64];
  const int tid = threadIdx.x;
  const int w = tid >> 6, l = tid & 63;
  const int c = blockIdx.z;
  const int m0 = blockIdx.y * 128, n0 = blockIdx.x * 128;
  const _Float16* Ab = A + (size_t)c * ACS + (size_t)m0 * LDA;
  const _Float16* Bb = Bm + (size_t)c * BCS + (size_t)n0 * LDB;
  f32x4 acc[4][4];
#pragma unroll
  for (int i = 0; i < 4; ++i)
#pragma unroll
    for (int j = 0; j < 4; ++j) acc[i][j] = (f32x4)0.0f;
  const int wm = (w >> 1) * 64, wn = (w & 1) * 64;
  const int srow = l >> 3, sj = l & 7;
#pragma unroll 1
  for (int kb = 0; kb < KK / 64; ++kb) {
    // stage: LDS linear dest, XOR-swizzled global source (chunk j stored at j^(r&7))
#pragma unroll
    for (int q = 0; q < 4; ++q) {
      int r = w * 32 + q * 8 + srow;
      int gj = sj ^ (r & 7);
      gload16(Ab + (size_t)r * LDA + kb * 64 + gj * 8, &Asl[(w * 32 + q * 8) * 64]);
      gload16(Bb + (size_t)r * LDB + kb * 64 + gj * 8, &Bsl[(w * 32 + q * 8) * 64]);
    }
    __syncthreads();
#pragma unroll
    for (int s2 = 0; s2 < 2; ++s2) {
      f16x8 af[4], bf[4];
#pragma unroll
      for (int i = 0; i < 4; ++i) {
        int R = wm + i * 16 + (l & 15);
        int p = (s2 * 4 + (l >> 4)) ^ (R & 7);
        af[i] = *(const f16x8*)&Asl[R * 64 + p * 8];
        int RN = wn + i * 16 + (l & 15);
        int pn = (s2 * 4 + (l >> 4)) ^ (RN & 7);
        bf[i] = *(const f16x8*)&Bsl[RN * 64 + pn * 8];
      }
#pragma unroll
      for (int i = 0; i < 4; ++i)
#pragma unroll
        for (int j = 0; j < 4; ++j)
          acc[i][j] = __builtin_amdgcn_mfma_f32_16x16x32_f16(af[i], bf[j], acc[i][j], 0, 0, 0);
    }
    __syncthreads();
  }
  const int rl = (l >> 4) * 4, cl = l & 15;
  if (EPI == 3) {
    // columns n' = n0+wn + j*16 + cl : gate j of h-index hh
    const int hh = (((n0 + wn) >> 6) << 4) + cl;
    float bv[4];
#pragma unroll
    for (int j = 0; j < 4; ++j) bv[j] = bias[(size_t)c * BLD + (n0 + wn) + j * 16 + cl];
#pragma unroll
    for (int i = 0; i < 4; ++i) {
#pragma unroll
      for (int rg = 0; rg < 4; ++rg) {
        int row = m0 + wm + i * 16 + rl + rg;
        float ig = acc[i][0][rg] + bv[0];
        float fg = acc[i][1][rg] + bv[1];
        float gg = acc[i][2][rg] + bv[2];
        float og = acc[i][3][rg] + bv[3];
        size_t ci = ((size_t)c * 256 + row) * 512 + hh;
        float cn = sigm(fg) * cstate[ci] + sigm(ig) * tanhf(gg);
        cstate[ci] = cn;
        hdst[((size_t)c * 256 + row) * 1024 + 512 + hh] = (_Float16)(sigm(og) * tanhf(cn));
      }
    }
  } else {
    float gv = 0.0f;
    if (EPI == 2) gv = sigm(gl[c]);
#pragma unroll
    for (int i = 0; i < 4; ++i) {
#pragma unroll
      for (int j = 0; j < 4; ++j) {
        int gc = n0 + wn + j * 16 + cl;
        float bv = bias[(size_t)c * BLD + gc];
#pragma unroll
        for (int rg = 0; rg < 4; ++rg) {
          int gr = m0 + wm + i * 16 + rl + rg;
          float v = acc[i][j][rg] + bv;
          if (EPI == 0) v = fmaxf(v, 0.0f);
          if (EPI == 2) v = tanhf(v) * gv;
          hout[(size_t)c * (256 * (size_t)OLD) + (size_t)gr * OLD + gc] = (_Float16)v;
        }
      }
    }
  }
}

// ---------------- LN in place on Aq P-region (rows C*B, cols 0..511, ld 1024) ----------------
__global__ __launch_bounds__(256) void k_ln(_Float16* __restrict__ Aq,
                                            const float* __restrict__ g,
                                            const float* __restrict__ b) {
  int row = blockIdx.x * 4 + (threadIdx.x >> 6);
  int l = threadIdx.x & 63;
  int c = row >> 8;
  _Float16* p = Aq + (size_t)row * 1024 + l * 8;
  f16x8 v = *(const f16x8*)p;
  float vf[8];
  float s1 = 0.0f, s2 = 0.0f;
#pragma unroll
  for (int j = 0; j < 8; ++j) {
    vf[j] = (float)v[j];
    s1 += vf[j];
    s2 += vf[j] * vf[j];
  }
#pragma unroll
  for (int m = 1; m < 64; m <<= 1) {
    s1 += __shfl_xor(s1, m, 64);
    s2 += __shfl_xor(s2, m, 64);
  }
  float mu = s1 * (1.0f / 512.0f);
  float var = s2 * (1.0f / 512.0f) - mu * mu;
  float rs = rsqrtf(var + 1e-5f);
  int col0 = l * 8;
#pragma unroll
  for (int j = 0; j < 8; ++j) {
    float o = (vf[j] - mu) * rs * g[c * 512 + col0 + j] + b[c * 512 + col0 + j];
    v[j] = (_Float16)o;
  }
  *(f16x8*)p = v;
}

// ---------------- agg: y = mean_c(abuf); out[:,t,:]; xq_next = f16(xs[t+1] + 0.3 y) ----------------
__global__ __launch_bounds__(256) void k_agg(const _Float16* __restrict__ abuf,
                                             const _Float16* __restrict__ xs_h,
                                             _Float16* __restrict__ xq,
                                             float* __restrict__ out, int t) {
  int idx = blockIdx.x * 256 + threadIdx.x;  // < B*H/4
  int i4 = idx * 4;
  float s[4] = {0.0f, 0.0f, 0.0f, 0.0f};
#pragma unroll
  for (int c = 0; c < 16; ++c) {
    f16x4 a = *(const f16x4*)&abuf[(size_t)c * 131072 + i4];
#pragma unroll
    for (int j = 0; j < 4; ++j) s[j] += (float)a[j];
  }
  int b = i4 >> 9, h = i4 & 511;
  float4 y4;
  float* yp = &y4.x;
#pragma unroll
  for (int j = 0; j < 4; ++j) yp[j] = s[j] * (1.0f / 16.0f);
  *(float4*)&out[((size_t)b * T + t) * 512 + h] = y4;
  if (t + 1 < T) {
    f16x4 xs4 = *(const f16x4*)&xs_h[(size_t)(t + 1) * 131072 + i4];
    f16x4 xn;
#pragma unroll
    for (int j = 0; j < 4; ++j) xn[j] = (_Float16)((float)xs4[j] + 0.3f * yp[j]);
    *(f16x4*)&xq[i4] = xn;
  }
}

extern "C" void kernel_launch(void* const* d_in, const int* in_sizes, int n_in,
                              void* d_out, int out_size, void* d_ws, size_t ws_size,
                              hipStream_t stream) {
  const int* tokens = (const int*)d_in[0];
  const float* emb = (const float*)d_in[1];
  const float* Wproj = (const float*)d_in[2];
  const float* bproj = (const float*)d_in[3];
  const float* Wp = (const float*)d_in[4];
  const float* bp = (const float*)d_in[5];
  const float* ln_g = (const float*)d_in[6];
  const float* ln_b = (const float*)d_in[7];
  const float* Wih = (const float*)d_in[8];
  const float* bih = (const float*)d_in[9];
  const float* Whh = (const float*)d_in[10];
  const float* bhh = (const float*)d_in[11];
  const float* Wa = (const float*)d_in[12];
  const float* ba = (const float*)d_in[13];
  const float* gl = (const float*)d_in[14];
  float* out = (float*)d_out;

  char* w8 = (char*)d_ws;
  _Float16* xs_h = (_Float16*)w8;                        // 33,554,432 B
  _Float16* Aq0 = (_Float16*)(w8 + 33554432);            // 16,777,216 B  [c][256][1024] P|h
  _Float16* Aq1 = (_Float16*)(w8 + 50331648);            // 16,777,216 B  ping-pong
  float* cbuf = (float*)(w8 + 67108864);                 //  8,388,608 B
  _Float16* abuf = (_Float16*)(w8 + 75497472);           //  4,194,304 B
  _Float16* xq = (_Float16*)(w8 + 79691776);             //    262,144 B
  _Float16* WpT = (_Float16*)(w8 + 79953920);            //  8,388,608 B
  _Float16* WaT = (_Float16*)(w8 + 88342528);            //  8,388,608 B
  _Float16* WgT = (_Float16*)(w8 + 96731136);            // 67,108,864 B
  float* bsum = (float*)(w8 + 163840000);                //    131,072 B (end 163,971,072)

  hipMemsetAsync(Aq0, 0, 16777216, stream);  // h0 = 0 (step 0 reads Aq0 h-region)
  hipMemsetAsync(cbuf, 0, 8388608, stream);  // c0 = 0

  k_cvt_wg<<<4096, 256, 0, stream>>>(Wih, Whh, WgT);
  k_cvt_tr<<<dim3(8, 8, 16), 256, 0, stream>>>(Wp, WpT);
  k_cvt_tr<<<dim3(8, 8, 16), 256, 0, stream>>>(Wa, WaT);
  k_bias<<<128, 256, 0, stream>>>(bih, bhh, bsum);
  k_emb<<<T * B / 16, 256, 0, stream>>>(tokens, emb, Wproj, bproj, xs_h);
  hipMemcpyAsync(xq, xs_h, 262144, hipMemcpyDeviceToDevice, stream);  // x0 (ext=0)

  for (int t = 0; t < T; ++t) {
    _Float16* Ac = (t & 1) ? Aq1 : Aq0;   // current: P written here; holds h from t-1
    _Float16* An = (t & 1) ? Aq0 : Aq1;   // next: new h written here
    // percept: A=xq[256][512] (shared over c), B=WpT[c][512][512] -> Ac P region (relu)
    k_gemm<0, 512, 512, 512, 0, 262144, 1024, 512>
        <<<dim3(4, 2, 16), 256, 0, stream>>>(xq, WpT, Ac, bp, nullptr, nullptr, nullptr);
    k_ln<<<1024, 256, 0, stream>>>(Ac, ln_g, ln_b);
    // gates+LSTM: A=Ac[c][256][1024] (P|h), B=WgT interleaved -> cbuf, h into An
    k_gemm<3, 1024, 1024, 1024, 262144, 2097152, 1, 2048>
        <<<dim3(16, 2, 16), 256, 0, stream>>>(Ac, WgT, nullptr, bsum, nullptr, cbuf, An);
    // assoc: A=An h region (ld 1024), B=WaT[c][512][512] -> abuf (tanh * gate)
    k_gemm<2, 512, 1024, 512, 262144, 262144, 512, 512>
        <<<dim3(4, 2, 16), 256, 0, stream>>>(An + 512, WaT, abuf, ba, gl, nullptr, nullptr);
    k_agg<<<128, 256, 0, stream>>>(abuf, xs_h, xq, out, t);
  }
}